// Round 21
// baseline (326.631 us; speedup 1.0000x reference)
//
#include <hip/hip_runtime.h>

typedef unsigned int  u32;
typedef unsigned long long u64;
typedef unsigned short u16;
typedef __attribute__((ext_vector_type(8))) _Float16 h8;   // MFMA A/B frag: 8 fp16 = 4 VGPR
typedef __attribute__((ext_vector_type(2))) _Float16 h2;   // packed fp16 pair
typedef __attribute__((ext_vector_type(4))) float    f4;   // MFMA C/D frag

#define RS    136    // X row stride (fp16): 272B rows, 16B-aligned
#define PRS   40     // row stride for vde weights (K=18 padded to 32, stored 40)
#define PIXB  128    // pixels per block (2 px-groups x 64 px)
#define WOFF  5120   // vde region size (halves)
#define FULLT 16384  // one fragment-major weight tile (halves)
#define MFMA16 __builtin_amdgcn_mfma_f32_16x16x32_f16

__device__ __forceinline__ u16 f2h(float f) {
  _Float16 h = (_Float16)f;
  return __builtin_bit_cast(u16, h);
}
__device__ __forceinline__ u32 pkrtz(float a, float b) {
  return __builtin_bit_cast(u32, __builtin_amdgcn_cvt_pkrtz(a, b));
}
__device__ __forceinline__ u32 pkmul(u32 a, u32 b) {   // v_pk_mul_f16
  h2 r = __builtin_bit_cast(h2, a) * __builtin_bit_cast(h2, b);
  return __builtin_bit_cast(u32, r);
}
__device__ __forceinline__ u32 pkmax0(u32 a) {         // v_pk_max_f16 vs 0
  h2 z = {(_Float16)0.f, (_Float16)0.f};
  h2 r = __builtin_elementwise_max(__builtin_bit_cast(h2, a), z);
  return __builtin_bit_cast(u32, r);
}

// ---------------------------------------------------------------------------
// Prep: fp16 weights in FRAGMENT-MAJOR layout for coalesced A-frag loads.
// ws (halves): [0,5120) vdeT [128][40] (k<18 valid).
//   [5120 + j*16384), j=0..11: per tile, chunks [nt(8)][ks(4)][lane(64)][8]:
//   lane = g*16+r holds W[n = nt*16+r][k = ks*32+g*8 .. +7] — one
//   global_load_dwordx4 at (base + chunk*1024 + lane*16) IS the A-frag.
//   j: 0..2 vh, 3..8 hid, 9 headW0, 10 headW1, 11 headW2 (n>=4 zero)
// ---------------------------------------------------------------------------
__global__ __launch_bounds__(256) void rc_prep(
    const float* __restrict__ vde_W, const float* __restrict__ vh_W,
    const float* __restrict__ hid_W, const float* __restrict__ head_W0,
    const float* __restrict__ head_W1, const float* __restrict__ head_W2,
    u16* __restrict__ ws)
{
  const int TOT = WOFF + 12 * FULLT;   // 201728
  int i = blockIdx.x * 256 + threadIdx.x;
  if (i >= TOT) return;
  float val = 0.f;
  if (i < WOFF) {
    int n = i / PRS, k = i - n * PRS;
    if (k < 18) val = vde_W[k * 128 + n];
  } else {
    int t  = i - WOFF;
    int j  = t >> 14;          // tile
    int c  = t & 16383;
    int nt = c >> 11;          // output-channel tile
    int ks = (c >> 9) & 3;     // k-step
    int ln = (c >> 3) & 63;    // lane
    int e  = c & 7;            // element within frag
    int r  = ln & 15, g = ln >> 4;
    int n  = nt * 16 + r;
    int k  = ks * 32 + g * 8 + e;
    if (j < 3)        val = vh_W[j * 16384 + k * 128 + n];
    else if (j < 9)   val = hid_W[(j - 3) * 16384 + k * 128 + n];
    else if (j == 9)  val = head_W0[k * 128 + n];
    else if (j == 10) val = head_W1[k * 128 + n];
    else              val = (n < 4) ? head_W2[k * 4 + n] : 0.f;
  }
  ws[i] = f2h(val);
}

// ---------------------------------------------------------------------------
// Inline-asm weight loads. HARD RULES (R13/R15 aborts): every issued load is
// consumed via a counted WAITV within the SAME layer body; nothing is ever
// in flight across __syncthreads, the gather, or kernel exit.
// ---------------------------------------------------------------------------
#define GLOAD(dst, base, voff, immstr)                                        \
  asm volatile("global_load_dwordx4 %0, %1, %2 offset:" immstr               \
               : "=v"(dst) : "v"(voff), "s"(base) : "memory")

#define ISSUE(S, NTL) do {                                                    \
  u32 vo_ = aoff + (NTL) * 4096;                                              \
  GLOAD(Ar##S[0], wbase, vo_, "0");                                           \
  GLOAD(Ar##S[1], wbase, vo_, "1024");                                        \
  GLOAD(Ar##S[2], wbase, vo_, "2048");                                        \
  GLOAD(Ar##S[3], wbase, vo_, "3072");                                        \
} while (0)

#define WAITV(nstr) do {                                                      \
  asm volatile("s_waitcnt vmcnt(" nstr ")" ::: "memory");                     \
  __builtin_amdgcn_sched_barrier(0);                                          \
} while (0)

// epilogue for one nt tile from persistent accumulators AC[4]:
// cvt_pkrtz -> packed relu -> [capture | pk_mul modulate] -> ds_write_b64.
#define EPI(NTL, AC) do {                                                     \
  const int col = nbase + (NTL) * 16 + 4 * g;                                 \
  _Pragma("unroll")                                                           \
  for (int t = 0; t < 4; ++t) {                                               \
    u32 lo = pkmax0(pkrtz(AC[t][0], AC[t][1]));                               \
    u32 hi = pkmax0(pkrtz(AC[t][2], AC[t][3]));                               \
    if (mode == 1) {                       /* capture vh (packed) */          \
      vhp[t][NTL][0] = lo; vhp[t][NTL][1] = hi;                               \
    } else {                                                                  \
      if (mode == 2) {                     /* h = relu(out) * vh */           \
        lo = pkmul(lo, vhp[t][NTL][0]);                                       \
        hi = pkmul(hi, vhp[t][NTL][1]);                                       \
      }                                                                       \
      *(uint2*)&X[xr[t] + col] = make_uint2(lo, hi);                          \
    }                                                                         \
  }                                                                           \
} while (0)

// one full 128x128 layer at 64px x 32ch per wave, IN-PLACE X update:
// ks-loop (all X reads) -> race barrier -> EPI writes [/gather] -> barrier.
// Dual-nt accumulation (ac0/ac1 = 32 persistent VGPRs), x streamed per-ks
// (16 transient VGPRs, read-once). 8 asm loads/layer, WAITV(4/0) inside
// the ks-loop — all drained before the race barrier.
#define LAYER(LI) do {                                                        \
  const int li   = (LI);                                                      \
  const int blb  = (li + 1) * 128;                                            \
  const int mode = (li == 2) ? 1 : (li == 5) ? 2 : 0;                         \
  const u64 wbase = (u64)(uintptr_t)(ws + WOFF + li * FULLT);                 \
  ISSUE(0, 0); ISSUE(1, 1);        /* 8 loads in flight */                    \
  f4 b0 = *(const f4*)&BL[blb + nbase + 4 * g];                               \
  f4 b1 = *(const f4*)&BL[blb + nbase + 16 + 4 * g];                          \
  f4 ac0[4] = {b0, b0, b0, b0};                                               \
  f4 ac1[4] = {b1, b1, b1, b1};                                               \
  _Pragma("unroll")                                                           \
  for (int ks = 0; ks < 4; ++ks) {                                            \
    h8 xk0 = *(const h8*)&X[xr[0] + ks * 32 + g * 8];                         \
    h8 xk1 = *(const h8*)&X[xr[1] + ks * 32 + g * 8];                         \
    h8 xk2 = *(const h8*)&X[xr[2] + ks * 32 + g * 8];                         \
    h8 xk3 = *(const h8*)&X[xr[3] + ks * 32 + g * 8];                         \
    if (ks == 0) WAITV("4");       /* Ar0 landed */                           \
    ac0[0] = MFMA16(Ar0[ks], xk0, ac0[0], 0, 0, 0);                           \
    ac0[1] = MFMA16(Ar0[ks], xk1, ac0[1], 0, 0, 0);                           \
    ac0[2] = MFMA16(Ar0[ks], xk2, ac0[2], 0, 0, 0);                           \
    ac0[3] = MFMA16(Ar0[ks], xk3, ac0[3], 0, 0, 0);                           \
    if (ks == 0) WAITV("0");       /* Ar1 landed; all asm loads drained */    \
    ac1[0] = MFMA16(Ar1[ks], xk0, ac1[0], 0, 0, 0);                           \
    ac1[1] = MFMA16(Ar1[ks], xk1, ac1[1], 0, 0, 0);                           \
    ac1[2] = MFMA16(Ar1[ks], xk2, ac1[2], 0, 0, 0);                           \
    ac1[3] = MFMA16(Ar1[ks], xk3, ac1[3], 0, 0, 0);                           \
  }                                                                           \
  __syncthreads();                 /* all waves' X reads complete */          \
  EPI(0, ac0);                                                                \
  EPI(1, ac1);                                                                \
  if (li == 2) do_gather();                                                   \
  __syncthreads();                 /* X writes published */                   \
} while (0)

// ---------------------------------------------------------------------------
// Main fused kernel — port-split, 64px x 32ch per wave, dual-nt k-streamed
// accumulation, SINGLE X buffer (in-place + race barrier) to shrink LDS to
// 41.5 KB -> 3 blocks/CU at __launch_bounds__(512,6): 24 waves/CU (6/SIMD),
// +50% TLP vs R20's ping-pong. 8 waves = 2 px-groups x 4 ch-quarters.
// ---------------------------------------------------------------------------
__global__ __launch_bounds__(512, 6) void rc_main(
    const int*   __restrict__ vert,  const float* __restrict__ bary,
    const float* __restrict__ view,  const float* __restrict__ emb,
    const float* __restrict__ vde_b, const float* __restrict__ vh_b,
    const float* __restrict__ hid_b, const float* __restrict__ head_b0,
    const float* __restrict__ head_b1, const float* __restrict__ head_b2,
    const u16*   __restrict__ ws,    float* __restrict__ out)
{
  __shared__ __align__(16) u16   X[PIXB * RS];   // 34816 B activations
  __shared__ __align__(16) float BL[1664];       // 6656 B: all biases

  const int tid  = threadIdx.x;
  const int lane = tid & 63;
  const int w    = tid >> 6;        // wave 0..7
  const int pg   = w >> 2;          // pixel group 0..1 (64 px each)
  const int cq   = w & 3;           // channel quarter 0..3 (32 ch each)
  const int r    = lane & 15;       // pixel-within-tile; A row
  const int g    = lane >> 4;       // k-group; D row group
  const int pbase = pg * 64;        // wave's first pixel row (64 px/wave)
  const int nbase = cq * 32;        // wave's first output channel
  const u32 aoff  = (u32)(cq * 8192 + lane * 16); // byte offset of frag chunk
  const size_t bpix = (size_t)blockIdx.x * PIXB;

  // ---- cooperative bias load into LDS
  for (int i = tid; i < 1664; i += 512) {
    float v;
    if      (i < 128)  v = vde_b[i];
    else if (i < 512)  v = vh_b[i - 128];
    else if (i < 1280) v = hid_b[i - 512];
    else if (i < 1408) v = head_b0[i - 1280];
    else if (i < 1536) v = head_b1[i - 1408];
    else if (i < 1540) v = head_b2[i - 1536];
    else               v = 0.f;
    BL[i] = v;
  }

  // ---- PE: threads 0..127 compute one pixel's encoding into X[row][0..32)
  if (tid < PIXB) {
    const int p = tid;
    const float* vd = view + (bpix + p) * 3;
    const float SG0 = 6.28318530718f;   // 2pi / 0.9^0
    const float SG1 = 6.50777324f;      // 2pi / 0.9^(1/3)
    const float SG2 = 6.74038866f;      // 2pi / 0.9^(2/3)
    u32 pw[16];
#pragma unroll
    for (int i = 0; i < 3; ++i) {
      float x = vd[i];
      float s0 = __sinf(x * SG0), c0 = __cosf(x * SG0);
      float s1 = __sinf(x * SG1), c1 = __cosf(x * SG1);
      float s2 = __sinf(x * SG2), c2 = __cosf(x * SG2);
      pw[i * 3 + 0] = (u32)f2h(s0) | ((u32)f2h(s1) << 16);
      pw[i * 3 + 1] = (u32)f2h(s2) | ((u32)f2h(c0) << 16);
      pw[i * 3 + 2] = (u32)f2h(c1) | ((u32)f2h(c2) << 16);
    }
#pragma unroll
    for (int q = 9; q < 16; ++q) pw[q] = 0u;   // zero-pad k = 18..31
    uint4* dst = (uint4*)&X[p * RS];
#pragma unroll
    for (int q = 0; q < 4; ++q)
      dst[q] = make_uint4(pw[4*q], pw[4*q+1], pw[4*q+2], pw[4*q+3]);
  }
  __syncthreads();   // PE published

  const int xr[4] = { (pbase +      r) * RS, (pbase + 16 + r) * RS,
                      (pbase + 32 + r) * RS, (pbase + 48 + r) * RS };

  // ---- gather closure (used at li==2): embedding + renorm + bary -> X.
  // wave w owns px [w*16, w*16+16); 16-lane group g handles 4 of them.
  auto do_gather = [&]() {
#pragma unroll 4
    for (int i = 0; i < 4; ++i) {
      int p = w * 16 + g * 4 + i;
      size_t gp = bpix + p;
      const int*   vi = vert + gp * 3;
      const float* by = bary + gp * 3;
      f4 va = {0.f,0.f,0.f,0.f}, vb = {0.f,0.f,0.f,0.f};
#pragma unroll
      for (int vt = 0; vt < 3; ++vt) {
        int id = vi[vt] + 1;
        const float* row = emb + (size_t)id * 128 + r * 8;  // lane r: 8 chans
        f4 e0 = *(const f4*)row;
        f4 e1 = *(const f4*)(row + 4);
        float ss = e0[0]*e0[0] + e0[1]*e0[1] + e0[2]*e0[2] + e0[3]*e0[3]
                 + e1[0]*e1[0] + e1[1]*e1[1] + e1[2]*e1[2] + e1[3]*e1[3];
        ss += __shfl_xor(ss, 1);             // reduce within the 16-lane group
        ss += __shfl_xor(ss, 2);
        ss += __shfl_xor(ss, 4);
        ss += __shfl_xor(ss, 8);
        float nrm = sqrtf(ss);
        float sc  = (nrm > 1.f) ? (1.f / (nrm + 1e-7f)) : 1.f;  // torch max_norm
        float wt  = by[vt] * sc;
#pragma unroll
        for (int j = 0; j < 4; ++j) { va[j] += wt * e0[j]; vb[j] += wt * e1[j]; }
      }
      h8 o;
#pragma unroll
      for (int j = 0; j < 4; ++j) { o[j] = (_Float16)va[j]; o[j+4] = (_Float16)vb[j]; }
      *(h8*)&X[p * RS + r * 8] = o;
    }
  };

  // ---- vde (K=18 padded to 32): in-place X update with race barrier
  {
    h8 Av[2];
#pragma unroll
    for (int ntl = 0; ntl < 2; ++ntl)
      Av[ntl] = *(const h8*)&ws[(nbase + ntl * 16 + r) * PRS + g * 8];
    h8 pe[4];
#pragma unroll
    for (int t = 0; t < 4; ++t) pe[t] = *(const h8*)&X[xr[t] + g * 8];
    __syncthreads();   // all PE reads in regs; X now writable
#pragma unroll
    for (int ntl = 0; ntl < 2; ++ntl) {
      f4 bini = *(const f4*)&BL[nbase + ntl * 16 + 4 * g];
      const int col = nbase + ntl * 16 + 4 * g;
#pragma unroll
      for (int t = 0; t < 4; ++t) {
        f4 acc = MFMA16(Av[ntl], pe[t], bini, 0, 0, 0);
        *(uint2*)&X[xr[t] + col] =          // no relu on vde output
          make_uint2(pkrtz(acc[0], acc[1]), pkrtz(acc[2], acc[3]));
      }
    }
  }
  __syncthreads();   // X (vde out) published

  // ---- 11 full 128x128 layers, in-place X, 2 barriers/layer
  u32 vhp[4][2][2];            // captured vh: set at li==2, used at li==5
  h8 Ar0[4], Ar1[4];           // 2-slot ring (32 VGPRs)
  LAYER(0);  LAYER(1);  LAYER(2);  LAYER(3);
  LAYER(4);  LAYER(5);  LAYER(6);  LAYER(7);
  LAYER(8);  LAYER(9);  LAYER(10);

  // ---- head_W2 (128 -> 4) + head_b2 from X; compiler-scheduled weights
  if (cq == 0) {
    const u16* wa = ws + WOFF + 11 * FULLT;
    f4 b2 = *(const f4*)&BL[1536 + 4 * g];   // g==0 lanes: real head_b2
    f4 acc[4] = {b2, b2, b2, b2};
#pragma unroll
    for (int ks = 0; ks < 4; ++ks) {
      h8 A = *(const h8*)&wa[ks * 512 + lane * 8];
#pragma unroll
      for (int t = 0; t < 4; ++t) {
        h8 xt = *(const h8*)&X[xr[t] + ks * 32 + g * 8];
        acc[t] = MFMA16(A, xt, acc[t], 0, 0, 0);
      }
    }
    if (g == 0) {                      // lane r holds pixel r's rgba contiguously
#pragma unroll
      for (int t = 0; t < 4; ++t)
        *(f4*)&out[(bpix + pbase + t * 16 + r) * 4] = acc[t];
    }
  }
}

// ---------------------------------------------------------------------------
extern "C" void kernel_launch(void* const* d_in, const int* in_sizes, int n_in,
                              void* d_out, int out_size, void* d_ws, size_t ws_size,
                              hipStream_t stream) {
  const int*   vert    = (const int*)  d_in[0];
  const float* bary    = (const float*)d_in[1];
  const float* view    = (const float*)d_in[2];
  const float* emb     = (const float*)d_in[3];
  const float* vde_W   = (const float*)d_in[4];
  const float* vde_b   = (const float*)d_in[5];
  const float* vh_W    = (const float*)d_in[6];
  const float* vh_b    = (const float*)d_in[7];
  const float* hid_W   = (const float*)d_in[8];
  const float* hid_b   = (const float*)d_in[9];
  const float* head_W0 = (const float*)d_in[10];
  const float* head_b0 = (const float*)d_in[11];
  const float* head_W1 = (const float*)d_in[12];
  const float* head_b1 = (const float*)d_in[13];
  const float* head_W2 = (const float*)d_in[14];
  const float* head_b2 = (const float*)d_in[15];
  u16* wsp = (u16*)d_ws;   // needs 403456 B

  rc_prep<<<788, 256, 0, stream>>>(vde_W, vh_W, hid_W, head_W0, head_W1, head_W2, wsp);
  rc_main<<<4096, 512, 0, stream>>>(vert, bary, view, emb, vde_b, vh_b, hid_b,
                                    head_b0, head_b1, head_b2, wsp, (float*)d_out);
}

// Round 22
// 291.487 us; speedup vs baseline: 1.1206x; 1.1206x over previous
//
#include <hip/hip_runtime.h>

typedef unsigned int  u32;
typedef unsigned long long u64;
typedef unsigned short u16;
typedef __attribute__((ext_vector_type(8))) _Float16 h8;   // MFMA A/B frag: 8 fp16 = 4 VGPR
typedef __attribute__((ext_vector_type(2))) _Float16 h2;   // packed fp16 pair
typedef __attribute__((ext_vector_type(4))) float    f4;   // MFMA C/D frag

#define RS    136    // X row stride (fp16): 272B rows, 16B-aligned
#define PRS   40     // row stride for vde weights (K=18 padded to 32, stored 40)
#define PIXB  128    // pixels per block (2 px-groups x 64 px)
#define WOFF  5120   // vde region size (halves)
#define FULLT 16384  // one fragment-major weight tile (halves)
#define MFMA16 __builtin_amdgcn_mfma_f32_16x16x32_f16

__device__ __forceinline__ u16 f2h(float f) {
  _Float16 h = (_Float16)f;
  return __builtin_bit_cast(u16, h);
}
__device__ __forceinline__ u32 pkrtz(float a, float b) {
  return __builtin_bit_cast(u32, __builtin_amdgcn_cvt_pkrtz(a, b));
}
__device__ __forceinline__ u32 pkmul(u32 a, u32 b) {   // v_pk_mul_f16
  h2 r = __builtin_bit_cast(h2, a) * __builtin_bit_cast(h2, b);
  return __builtin_bit_cast(u32, r);
}
__device__ __forceinline__ u32 pkmax0(u32 a) {         // v_pk_max_f16 vs 0
  h2 z = {(_Float16)0.f, (_Float16)0.f};
  h2 r = __builtin_elementwise_max(__builtin_bit_cast(h2, a), z);
  return __builtin_bit_cast(u32, r);
}

// ---------------------------------------------------------------------------
// Prep: fp16 weights in FRAGMENT-MAJOR layout for coalesced A-frag loads.
// ws (halves): [0,5120) vdeT [128][40] (k<18 valid).
//   [5120 + j*16384), j=0..11: per tile, chunks [nt(8)][ks(4)][lane(64)][8]:
//   lane = g*16+r holds W[n = nt*16+r][k = ks*32+g*8 .. +7] — one
//   global_load_dwordx4 at (base + chunk*1024 + lane*16) IS the A-frag.
//   j: 0..2 vh, 3..8 hid, 9 headW0, 10 headW1, 11 headW2 (n>=4 zero)
// ---------------------------------------------------------------------------
__global__ __launch_bounds__(256) void rc_prep(
    const float* __restrict__ vde_W, const float* __restrict__ vh_W,
    const float* __restrict__ hid_W, const float* __restrict__ head_W0,
    const float* __restrict__ head_W1, const float* __restrict__ head_W2,
    u16* __restrict__ ws)
{
  const int TOT = WOFF + 12 * FULLT;   // 201728
  int i = blockIdx.x * 256 + threadIdx.x;
  if (i >= TOT) return;
  float val = 0.f;
  if (i < WOFF) {
    int n = i / PRS, k = i - n * PRS;
    if (k < 18) val = vde_W[k * 128 + n];
  } else {
    int t  = i - WOFF;
    int j  = t >> 14;          // tile
    int c  = t & 16383;
    int nt = c >> 11;          // output-channel tile
    int ks = (c >> 9) & 3;     // k-step
    int ln = (c >> 3) & 63;    // lane
    int e  = c & 7;            // element within frag
    int r  = ln & 15, g = ln >> 4;
    int n  = nt * 16 + r;
    int k  = ks * 32 + g * 8 + e;
    if (j < 3)        val = vh_W[j * 16384 + k * 128 + n];
    else if (j < 9)   val = hid_W[(j - 3) * 16384 + k * 128 + n];
    else if (j == 9)  val = head_W0[k * 128 + n];
    else if (j == 10) val = head_W1[k * 128 + n];
    else              val = (n < 4) ? head_W2[k * 4 + n] : 0.f;
  }
  ws[i] = f2h(val);
}

// ---------------------------------------------------------------------------
// Inline-asm weight loads. HARD RULES (R13/R15 aborts): every issued load is
// consumed via a counted WAITV within the SAME layer body; nothing is ever
// in flight across __syncthreads, the gather, or kernel exit.
// ---------------------------------------------------------------------------
#define GLOAD(dst, base, voff, immstr)                                        \
  asm volatile("global_load_dwordx4 %0, %1, %2 offset:" immstr               \
               : "=v"(dst) : "v"(voff), "s"(base) : "memory")

#define ISSUE(S, NTL) do {                                                    \
  u32 vo_ = aoff + (NTL) * 4096;                                              \
  GLOAD(Ar##S[0], wbase, vo_, "0");                                           \
  GLOAD(Ar##S[1], wbase, vo_, "1024");                                        \
  GLOAD(Ar##S[2], wbase, vo_, "2048");                                        \
  GLOAD(Ar##S[3], wbase, vo_, "3072");                                        \
} while (0)

#define WAITV(nstr) do {                                                      \
  asm volatile("s_waitcnt vmcnt(" nstr ")" ::: "memory");                     \
  __builtin_amdgcn_sched_barrier(0);                                          \
} while (0)

// epilogue for one nt tile from persistent accumulators AC[4]:
// cvt_pkrtz -> packed relu -> [capture | pk_mul modulate] -> ds_write_b64.
#define EPI(NTL, AC) do {                                                     \
  const int col = nbase + (NTL) * 16 + 4 * g;                                 \
  _Pragma("unroll")                                                           \
  for (int t = 0; t < 4; ++t) {                                               \
    u32 lo = pkmax0(pkrtz(AC[t][0], AC[t][1]));                               \
    u32 hi = pkmax0(pkrtz(AC[t][2], AC[t][3]));                               \
    if (mode == 1) {                       /* capture vh (packed) */          \
      vhp[t][NTL][0] = lo; vhp[t][NTL][1] = hi;                               \
    } else {                                                                  \
      if (mode == 2) {                     /* h = relu(out) * vh */           \
        lo = pkmul(lo, vhp[t][NTL][0]);                                       \
        hi = pkmul(hi, vhp[t][NTL][1]);                                       \
      }                                                                       \
      *(uint2*)&X[xr[t] + col] = make_uint2(lo, hi);                          \
    }                                                                         \
  }                                                                           \
} while (0)

// one full 128x128 layer at 64px x 32ch per wave, IN-PLACE X update:
// ks-loop (all X reads) -> race barrier -> EPI writes [/gather] -> barrier.
// Dual-nt accumulation (ac0/ac1 = 32 persistent VGPRs), x streamed per-ks
// (16 transient VGPRs, read-once). 8 asm loads/layer, WAITV(4/0) inside
// the ks-loop — all drained before the race barrier.
#define LAYER(LI) do {                                                        \
  const int li   = (LI);                                                      \
  const int blb  = (li + 1) * 128;                                            \
  const int mode = (li == 2) ? 1 : (li == 5) ? 2 : 0;                         \
  const u64 wbase = (u64)(uintptr_t)(ws + WOFF + li * FULLT);                 \
  ISSUE(0, 0); ISSUE(1, 1);        /* 8 loads in flight */                    \
  f4 b0 = *(const f4*)&BL[blb + nbase + 4 * g];                               \
  f4 b1 = *(const f4*)&BL[blb + nbase + 16 + 4 * g];                          \
  f4 ac0[4] = {b0, b0, b0, b0};                                               \
  f4 ac1[4] = {b1, b1, b1, b1};                                               \
  _Pragma("unroll")                                                           \
  for (int ks = 0; ks < 4; ++ks) {                                            \
    h8 xk0 = *(const h8*)&X[xr[0] + ks * 32 + g * 8];                         \
    h8 xk1 = *(const h8*)&X[xr[1] + ks * 32 + g * 8];                         \
    h8 xk2 = *(const h8*)&X[xr[2] + ks * 32 + g * 8];                         \
    h8 xk3 = *(const h8*)&X[xr[3] + ks * 32 + g * 8];                         \
    if (ks == 0) WAITV("4");       /* Ar0 landed */                           \
    ac0[0] = MFMA16(Ar0[ks], xk0, ac0[0], 0, 0, 0);                           \
    ac0[1] = MFMA16(Ar0[ks], xk1, ac0[1], 0, 0, 0);                           \
    ac0[2] = MFMA16(Ar0[ks], xk2, ac0[2], 0, 0, 0);                           \
    ac0[3] = MFMA16(Ar0[ks], xk3, ac0[3], 0, 0, 0);                           \
    if (ks == 0) WAITV("0");       /* Ar1 landed; all asm loads drained */    \
    ac1[0] = MFMA16(Ar1[ks], xk0, ac1[0], 0, 0, 0);                           \
    ac1[1] = MFMA16(Ar1[ks], xk1, ac1[1], 0, 0, 0);                           \
    ac1[2] = MFMA16(Ar1[ks], xk2, ac1[2], 0, 0, 0);                           \
    ac1[3] = MFMA16(Ar1[ks], xk3, ac1[3], 0, 0, 0);                           \
  }                                                                           \
  __syncthreads();                 /* all waves' X reads complete */          \
  EPI(0, ac0);                                                                \
  EPI(1, ac1);                                                                \
  if (li == 2) do_gather();                                                   \
  __syncthreads();                 /* X writes published */                   \
} while (0)

// ---------------------------------------------------------------------------
// Main fused kernel — port-split, 64px x 32ch per wave, dual-nt k-streamed
// accumulation, SINGLE X buffer (41.5 KB LDS). __launch_bounds__(512,4):
// the allocator target R20 proved spill-free (VGPR=64). With VGPR=64
// (8 waves/SIMD allowed) and 41.5 KB LDS (3 blocks/CU allowed), the RUNTIME
// schedules 3 blocks/CU = 6 waves/SIMD — R21's occupancy without R21's
// forced-40-VGPR spill (launch_bounds min-waves is an allocator hint, not
// a runtime cap).
// ---------------------------------------------------------------------------
__global__ __launch_bounds__(512, 4) void rc_main(
    const int*   __restrict__ vert,  const float* __restrict__ bary,
    const float* __restrict__ view,  const float* __restrict__ emb,
    const float* __restrict__ vde_b, const float* __restrict__ vh_b,
    const float* __restrict__ hid_b, const float* __restrict__ head_b0,
    const float* __restrict__ head_b1, const float* __restrict__ head_b2,
    const u16*   __restrict__ ws,    float* __restrict__ out)
{
  __shared__ __align__(16) u16   X[PIXB * RS];   // 34816 B activations
  __shared__ __align__(16) float BL[1664];       // 6656 B: all biases

  const int tid  = threadIdx.x;
  const int lane = tid & 63;
  const int w    = tid >> 6;        // wave 0..7
  const int pg   = w >> 2;          // pixel group 0..1 (64 px each)
  const int cq   = w & 3;           // channel quarter 0..3 (32 ch each)
  const int r    = lane & 15;       // pixel-within-tile; A row
  const int g    = lane >> 4;       // k-group; D row group
  const int pbase = pg * 64;        // wave's first pixel row (64 px/wave)
  const int nbase = cq * 32;        // wave's first output channel
  const u32 aoff  = (u32)(cq * 8192 + lane * 16); // byte offset of frag chunk
  const size_t bpix = (size_t)blockIdx.x * PIXB;

  // ---- cooperative bias load into LDS
  for (int i = tid; i < 1664; i += 512) {
    float v;
    if      (i < 128)  v = vde_b[i];
    else if (i < 512)  v = vh_b[i - 128];
    else if (i < 1280) v = hid_b[i - 512];
    else if (i < 1408) v = head_b0[i - 1280];
    else if (i < 1536) v = head_b1[i - 1408];
    else if (i < 1540) v = head_b2[i - 1536];
    else               v = 0.f;
    BL[i] = v;
  }

  // ---- PE: threads 0..127 compute one pixel's encoding into X[row][0..32)
  if (tid < PIXB) {
    const int p = tid;
    const float* vd = view + (bpix + p) * 3;
    const float SG0 = 6.28318530718f;   // 2pi / 0.9^0
    const float SG1 = 6.50777324f;      // 2pi / 0.9^(1/3)
    const float SG2 = 6.74038866f;      // 2pi / 0.9^(2/3)
    u32 pw[16];
#pragma unroll
    for (int i = 0; i < 3; ++i) {
      float x = vd[i];
      float s0 = __sinf(x * SG0), c0 = __cosf(x * SG0);
      float s1 = __sinf(x * SG1), c1 = __cosf(x * SG1);
      float s2 = __sinf(x * SG2), c2 = __cosf(x * SG2);
      pw[i * 3 + 0] = (u32)f2h(s0) | ((u32)f2h(s1) << 16);
      pw[i * 3 + 1] = (u32)f2h(s2) | ((u32)f2h(c0) << 16);
      pw[i * 3 + 2] = (u32)f2h(c1) | ((u32)f2h(c2) << 16);
    }
#pragma unroll
    for (int q = 9; q < 16; ++q) pw[q] = 0u;   // zero-pad k = 18..31
    uint4* dst = (uint4*)&X[p * RS];
#pragma unroll
    for (int q = 0; q < 4; ++q)
      dst[q] = make_uint4(pw[4*q], pw[4*q+1], pw[4*q+2], pw[4*q+3]);
  }
  __syncthreads();   // PE published

  const int xr[4] = { (pbase +      r) * RS, (pbase + 16 + r) * RS,
                      (pbase + 32 + r) * RS, (pbase + 48 + r) * RS };

  // ---- gather closure (used at li==2): embedding + renorm + bary -> X.
  // wave w owns px [w*16, w*16+16); 16-lane group g handles 4 of them.
  auto do_gather = [&]() {
#pragma unroll 4
    for (int i = 0; i < 4; ++i) {
      int p = w * 16 + g * 4 + i;
      size_t gp = bpix + p;
      const int*   vi = vert + gp * 3;
      const float* by = bary + gp * 3;
      f4 va = {0.f,0.f,0.f,0.f}, vb = {0.f,0.f,0.f,0.f};
#pragma unroll
      for (int vt = 0; vt < 3; ++vt) {
        int id = vi[vt] + 1;
        const float* row = emb + (size_t)id * 128 + r * 8;  // lane r: 8 chans
        f4 e0 = *(const f4*)row;
        f4 e1 = *(const f4*)(row + 4);
        float ss = e0[0]*e0[0] + e0[1]*e0[1] + e0[2]*e0[2] + e0[3]*e0[3]
                 + e1[0]*e1[0] + e1[1]*e1[1] + e1[2]*e1[2] + e1[3]*e1[3];
        ss += __shfl_xor(ss, 1);             // reduce within the 16-lane group
        ss += __shfl_xor(ss, 2);
        ss += __shfl_xor(ss, 4);
        ss += __shfl_xor(ss, 8);
        float nrm = sqrtf(ss);
        float sc  = (nrm > 1.f) ? (1.f / (nrm + 1e-7f)) : 1.f;  // torch max_norm
        float wt  = by[vt] * sc;
#pragma unroll
        for (int j = 0; j < 4; ++j) { va[j] += wt * e0[j]; vb[j] += wt * e1[j]; }
      }
      h8 o;
#pragma unroll
      for (int j = 0; j < 4; ++j) { o[j] = (_Float16)va[j]; o[j+4] = (_Float16)vb[j]; }
      *(h8*)&X[p * RS + r * 8] = o;
    }
  };

  // ---- vde (K=18 padded to 32): in-place X update with race barrier
  {
    h8 Av[2];
#pragma unroll
    for (int ntl = 0; ntl < 2; ++ntl)
      Av[ntl] = *(const h8*)&ws[(nbase + ntl * 16 + r) * PRS + g * 8];
    h8 pe[4];
#pragma unroll
    for (int t = 0; t < 4; ++t) pe[t] = *(const h8*)&X[xr[t] + g * 8];
    __syncthreads();   // all PE reads in regs; X now writable
#pragma unroll
    for (int ntl = 0; ntl < 2; ++ntl) {
      f4 bini = *(const f4*)&BL[nbase + ntl * 16 + 4 * g];
      const int col = nbase + ntl * 16 + 4 * g;
#pragma unroll
      for (int t = 0; t < 4; ++t) {
        f4 acc = MFMA16(Av[ntl], pe[t], bini, 0, 0, 0);
        *(uint2*)&X[xr[t] + col] =          // no relu on vde output
          make_uint2(pkrtz(acc[0], acc[1]), pkrtz(acc[2], acc[3]));
      }
    }
  }
  __syncthreads();   // X (vde out) published

  // ---- 11 full 128x128 layers, in-place X, 2 barriers/layer
  u32 vhp[4][2][2];            // captured vh: set at li==2, used at li==5
  h8 Ar0[4], Ar1[4];           // 2-slot ring (32 VGPRs)
  LAYER(0);  LAYER(1);  LAYER(2);  LAYER(3);
  LAYER(4);  LAYER(5);  LAYER(6);  LAYER(7);
  LAYER(8);  LAYER(9);  LAYER(10);

  // ---- head_W2 (128 -> 4) + head_b2 from X; compiler-scheduled weights
  if (cq == 0) {
    const u16* wa = ws + WOFF + 11 * FULLT;
    f4 b2 = *(const f4*)&BL[1536 + 4 * g];   // g==0 lanes: real head_b2
    f4 acc[4] = {b2, b2, b2, b2};
#pragma unroll
    for (int ks = 0; ks < 4; ++ks) {
      h8 A = *(const h8*)&wa[ks * 512 + lane * 8];
#pragma unroll
      for (int t = 0; t < 4; ++t) {
        h8 xt = *(const h8*)&X[xr[t] + ks * 32 + g * 8];
        acc[t] = MFMA16(A, xt, acc[t], 0, 0, 0);
      }
    }
    if (g == 0) {                      // lane r holds pixel r's rgba contiguously
#pragma unroll
      for (int t = 0; t < 4; ++t)
        *(f4*)&out[(bpix + pbase + t * 16 + r) * 4] = acc[t];
    }
  }
}

// ---------------------------------------------------------------------------
extern "C" void kernel_launch(void* const* d_in, const int* in_sizes, int n_in,
                              void* d_out, int out_size, void* d_ws, size_t ws_size,
                              hipStream_t stream) {
  const int*   vert    = (const int*)  d_in[0];
  const float* bary    = (const float*)d_in[1];
  const float* view    = (const float*)d_in[2];
  const float* emb     = (const float*)d_in[3];
  const float* vde_W   = (const float*)d_in[4];
  const float* vde_b   = (const float*)d_in[5];
  const float* vh_W    = (const float*)d_in[6];
  const float* vh_b    = (const float*)d_in[7];
  const float* hid_W   = (const float*)d_in[8];
  const float* hid_b   = (const float*)d_in[9];
  const float* head_W0 = (const float*)d_in[10];
  const float* head_b0 = (const float*)d_in[11];
  const float* head_W1 = (const float*)d_in[12];
  const float* head_b1 = (const float*)d_in[13];
  const float* head_W2 = (const float*)d_in[14];
  const float* head_b2 = (const float*)d_in[15];
  u16* wsp = (u16*)d_ws;   // needs 403456 B

  rc_prep<<<788, 256, 0, stream>>>(vde_W, vh_W, hid_W, head_W0, head_W1, head_W2, wsp);
  rc_main<<<4096, 512, 0, stream>>>(vert, bary, view, emb, vde_b, vh_b, hid_b,
                                    head_b0, head_b1, head_b2, wsp, (float*)d_out);
}

// Round 23
// 281.369 us; speedup vs baseline: 1.1609x; 1.0360x over previous
//
#include <hip/hip_runtime.h>

typedef unsigned int  u32;
typedef unsigned long long u64;
typedef unsigned short u16;
typedef __attribute__((ext_vector_type(8))) _Float16 h8;   // MFMA A/B frag: 8 fp16 = 4 VGPR
typedef __attribute__((ext_vector_type(2))) _Float16 h2;   // packed fp16 pair
typedef __attribute__((ext_vector_type(4))) float    f4;   // MFMA C/D frag

#define RS    136    // X row stride (fp16): 272B rows, 16B-aligned
#define PRS   40     // row stride for vde weights (K=18 padded to 32, stored 40)
#define PIXB  64     // pixels per block (4 waves share them; 1 px-group)
#define WOFF  5120   // vde region size (halves)
#define FULLT 16384  // one fragment-major weight tile (halves)
#define MFMA16 __builtin_amdgcn_mfma_f32_16x16x32_f16

__device__ __forceinline__ u16 f2h(float f) {
  _Float16 h = (_Float16)f;
  return __builtin_bit_cast(u16, h);
}
__device__ __forceinline__ u32 pkrtz(float a, float b) {
  return __builtin_bit_cast(u32, __builtin_amdgcn_cvt_pkrtz(a, b));
}
__device__ __forceinline__ u32 pkmul(u32 a, u32 b) {   // v_pk_mul_f16
  h2 r = __builtin_bit_cast(h2, a) * __builtin_bit_cast(h2, b);
  return __builtin_bit_cast(u32, r);
}
__device__ __forceinline__ u32 pkmax0(u32 a) {         // v_pk_max_f16 vs 0
  h2 z = {(_Float16)0.f, (_Float16)0.f};
  h2 r = __builtin_elementwise_max(__builtin_bit_cast(h2, a), z);
  return __builtin_bit_cast(u32, r);
}

// ---------------------------------------------------------------------------
// Prep: fp16 weights in FRAGMENT-MAJOR layout for coalesced A-frag loads.
// ws (halves): [0,5120) vdeT [128][40] (k<18 valid).
//   [5120 + j*16384), j=0..11: per tile, chunks [nt(8)][ks(4)][lane(64)][8]:
//   lane = g*16+r holds W[n = nt*16+r][k = ks*32+g*8 .. +7] — one
//   global_load_dwordx4 at (base + chunk*1024 + lane*16) IS the A-frag.
//   j: 0..2 vh, 3..8 hid, 9 headW0, 10 headW1, 11 headW2 (n>=4 zero)
// ---------------------------------------------------------------------------
__global__ __launch_bounds__(256) void rc_prep(
    const float* __restrict__ vde_W, const float* __restrict__ vh_W,
    const float* __restrict__ hid_W, const float* __restrict__ head_W0,
    const float* __restrict__ head_W1, const float* __restrict__ head_W2,
    u16* __restrict__ ws)
{
  const int TOT = WOFF + 12 * FULLT;   // 201728
  int i = blockIdx.x * 256 + threadIdx.x;
  if (i >= TOT) return;
  float val = 0.f;
  if (i < WOFF) {
    int n = i / PRS, k = i - n * PRS;
    if (k < 18) val = vde_W[k * 128 + n];
  } else {
    int t  = i - WOFF;
    int j  = t >> 14;          // tile
    int c  = t & 16383;
    int nt = c >> 11;          // output-channel tile
    int ks = (c >> 9) & 3;     // k-step
    int ln = (c >> 3) & 63;    // lane
    int e  = c & 7;            // element within frag
    int r  = ln & 15, g = ln >> 4;
    int n  = nt * 16 + r;
    int k  = ks * 32 + g * 8 + e;
    if (j < 3)        val = vh_W[j * 16384 + k * 128 + n];
    else if (j < 9)   val = hid_W[(j - 3) * 16384 + k * 128 + n];
    else if (j == 9)  val = head_W0[k * 128 + n];
    else if (j == 10) val = head_W1[k * 128 + n];
    else              val = (n < 4) ? head_W2[k * 4 + n] : 0.f;
  }
  ws[i] = f2h(val);
}

// ---------------------------------------------------------------------------
// Inline-asm weight loads. HARD RULES (R13/R15 aborts): every issued load is
// consumed via a counted WAITV within the SAME layer body; nothing is ever
// in flight across __syncthreads, the gather, or kernel exit.
// ---------------------------------------------------------------------------
#define GLOAD(dst, base, voff, immstr)                                        \
  asm volatile("global_load_dwordx4 %0, %1, %2 offset:" immstr               \
               : "=v"(dst) : "v"(voff), "s"(base) : "memory")

#define ISSUE(S, NTL) do {                                                    \
  u32 vo_ = aoff + (NTL) * 4096;                                              \
  GLOAD(Ar##S[0], wbase, vo_, "0");                                           \
  GLOAD(Ar##S[1], wbase, vo_, "1024");                                        \
  GLOAD(Ar##S[2], wbase, vo_, "2048");                                        \
  GLOAD(Ar##S[3], wbase, vo_, "3072");                                        \
} while (0)

#define WAITV(nstr) do {                                                      \
  asm volatile("s_waitcnt vmcnt(" nstr ")" ::: "memory");                     \
  __builtin_amdgcn_sched_barrier(0);                                          \
} while (0)

// epilogue for one nt tile from persistent accumulators AC[4]:
// cvt_pkrtz -> packed relu -> [capture | pk_mul modulate] -> ds_write_b64.
#define EPI(NTL, AC) do {                                                     \
  const int col = nbase + (NTL) * 16 + 4 * g;                                 \
  _Pragma("unroll")                                                           \
  for (int t = 0; t < 4; ++t) {                                               \
    u32 lo = pkmax0(pkrtz(AC[t][0], AC[t][1]));                               \
    u32 hi = pkmax0(pkrtz(AC[t][2], AC[t][3]));                               \
    if (mode == 1) {                       /* capture vh (packed) */          \
      vhp[t][NTL][0] = lo; vhp[t][NTL][1] = hi;                               \
    } else {                                                                  \
      if (mode == 2) {                     /* h = relu(out) * vh */           \
        lo = pkmul(lo, vhp[t][NTL][0]);                                       \
        hi = pkmul(hi, vhp[t][NTL][1]);                                       \
      }                                                                       \
      *(uint2*)&X[xr[t] + col] = make_uint2(lo, hi);                          \
    }                                                                         \
  }                                                                           \
} while (0)

// one full 128x128 layer at 64px x 32ch per wave, IN-PLACE X update:
// ks-loop (all X reads) -> race barrier -> EPI writes [/gather] -> barrier.
// Dual-nt accumulation (ac0/ac1 = 32 persistent VGPRs), x streamed per-ks
// (16 transient VGPRs, read-once). 8 asm loads/layer, WAITV(4/0) inside
// the ks-loop — all drained before the race barrier.
#define LAYER(LI) do {                                                        \
  const int li   = (LI);                                                      \
  const int blb  = (li + 1) * 128;                                            \
  const int mode = (li == 2) ? 1 : (li == 5) ? 2 : 0;                         \
  const u64 wbase = (u64)(uintptr_t)(ws + WOFF + li * FULLT);                 \
  ISSUE(0, 0); ISSUE(1, 1);        /* 8 loads in flight */                    \
  f4 b0 = *(const f4*)&BL[blb + nbase + 4 * g];                               \
  f4 b1 = *(const f4*)&BL[blb + nbase + 16 + 4 * g];                          \
  f4 ac0[4] = {b0, b0, b0, b0};                                               \
  f4 ac1[4] = {b1, b1, b1, b1};                                               \
  _Pragma("unroll")                                                           \
  for (int ks = 0; ks < 4; ++ks) {                                            \
    h8 xk0 = *(const h8*)&X[xr[0] + ks * 32 + g * 8];                         \
    h8 xk1 = *(const h8*)&X[xr[1] + ks * 32 + g * 8];                         \
    h8 xk2 = *(const h8*)&X[xr[2] + ks * 32 + g * 8];                         \
    h8 xk3 = *(const h8*)&X[xr[3] + ks * 32 + g * 8];                         \
    if (ks == 0) WAITV("4");       /* Ar0 landed */                           \
    ac0[0] = MFMA16(Ar0[ks], xk0, ac0[0], 0, 0, 0);                           \
    ac0[1] = MFMA16(Ar0[ks], xk1, ac0[1], 0, 0, 0);                           \
    ac0[2] = MFMA16(Ar0[ks], xk2, ac0[2], 0, 0, 0);                           \
    ac0[3] = MFMA16(Ar0[ks], xk3, ac0[3], 0, 0, 0);                           \
    if (ks == 0) WAITV("0");       /* Ar1 landed; all asm loads drained */    \
    ac1[0] = MFMA16(Ar1[ks], xk0, ac1[0], 0, 0, 0);                           \
    ac1[1] = MFMA16(Ar1[ks], xk1, ac1[1], 0, 0, 0);                           \
    ac1[2] = MFMA16(Ar1[ks], xk2, ac1[2], 0, 0, 0);                           \
    ac1[3] = MFMA16(Ar1[ks], xk3, ac1[3], 0, 0, 0);                           \
  }                                                                           \
  __syncthreads();                 /* all waves' X reads complete */          \
  EPI(0, ac0);                                                                \
  EPI(1, ac1);                                                                \
  if (li == 2) do_gather();                                                   \
  __syncthreads();                 /* X writes published */                   \
} while (0)

// ---------------------------------------------------------------------------
// Main fused kernel — port-split, 64px x 32ch per wave, dual-nt k-streamed
// accumulation, 256-THREAD BLOCKS: 4 waves = 4 ch-quarters over a shared
// 64-px tile. LDS = X (17.4 KB) + biases = 24 KB -> up to 6 blocks/CU;
// 4-wave barrier domains (vs 8) let co-resident blocks stagger freely.
// VGPR demand 64 (proven R20/R22) -> 8 waves/SIMD allowed by registers.
// ---------------------------------------------------------------------------
__global__ __launch_bounds__(256, 4) void rc_main(
    const int*   __restrict__ vert,  const float* __restrict__ bary,
    const float* __restrict__ view,  const float* __restrict__ emb,
    const float* __restrict__ vde_b, const float* __restrict__ vh_b,
    const float* __restrict__ hid_b, const float* __restrict__ head_b0,
    const float* __restrict__ head_b1, const float* __restrict__ head_b2,
    const u16*   __restrict__ ws,    float* __restrict__ out)
{
  __shared__ __align__(16) u16   X[PIXB * RS];   // 17408 B activations
  __shared__ __align__(16) float BL[1664];       // 6656 B: all biases

  const int tid  = threadIdx.x;
  const int lane = tid & 63;
  const int w    = tid >> 6;        // wave 0..3 = channel quarter
  const int r    = lane & 15;       // pixel-within-tile; A row
  const int g    = lane >> 4;       // k-group; D row group
  const int nbase = w * 32;         // wave's first output channel
  const u32 aoff  = (u32)(w * 8192 + lane * 16);  // byte offset of frag chunk
  const size_t bpix = (size_t)blockIdx.x * PIXB;

  // ---- cooperative bias load into LDS
  for (int i = tid; i < 1664; i += 256) {
    float v;
    if      (i < 128)  v = vde_b[i];
    else if (i < 512)  v = vh_b[i - 128];
    else if (i < 1280) v = hid_b[i - 512];
    else if (i < 1408) v = head_b0[i - 1280];
    else if (i < 1536) v = head_b1[i - 1408];
    else if (i < 1540) v = head_b2[i - 1536];
    else               v = 0.f;
    BL[i] = v;
  }

  // ---- PE: threads 0..63 compute one pixel's encoding into X[row][0..32)
  if (tid < PIXB) {
    const int p = tid;
    const float* vd = view + (bpix + p) * 3;
    const float SG0 = 6.28318530718f;   // 2pi / 0.9^0
    const float SG1 = 6.50777324f;      // 2pi / 0.9^(1/3)
    const float SG2 = 6.74038866f;      // 2pi / 0.9^(2/3)
    u32 pw[16];
#pragma unroll
    for (int i = 0; i < 3; ++i) {
      float x = vd[i];
      float s0 = __sinf(x * SG0), c0 = __cosf(x * SG0);
      float s1 = __sinf(x * SG1), c1 = __cosf(x * SG1);
      float s2 = __sinf(x * SG2), c2 = __cosf(x * SG2);
      pw[i * 3 + 0] = (u32)f2h(s0) | ((u32)f2h(s1) << 16);
      pw[i * 3 + 1] = (u32)f2h(s2) | ((u32)f2h(c0) << 16);
      pw[i * 3 + 2] = (u32)f2h(c1) | ((u32)f2h(c2) << 16);
    }
#pragma unroll
    for (int q = 9; q < 16; ++q) pw[q] = 0u;   // zero-pad k = 18..31
    uint4* dst = (uint4*)&X[p * RS];
#pragma unroll
    for (int q = 0; q < 4; ++q)
      dst[q] = make_uint4(pw[4*q], pw[4*q+1], pw[4*q+2], pw[4*q+3]);
  }
  __syncthreads();   // PE published

  const int xr[4] = { r * RS,        (16 + r) * RS,
                      (32 + r) * RS, (48 + r) * RS };

  // ---- gather closure (used at li==2): embedding + renorm + bary -> X.
  // wave w owns px [w*16, w*16+16); 16-lane group g handles 4 of them.
  auto do_gather = [&]() {
#pragma unroll 4
    for (int i = 0; i < 4; ++i) {
      int p = w * 16 + g * 4 + i;
      size_t gp = bpix + p;
      const int*   vi = vert + gp * 3;
      const float* by = bary + gp * 3;
      f4 va = {0.f,0.f,0.f,0.f}, vb = {0.f,0.f,0.f,0.f};
#pragma unroll
      for (int vt = 0; vt < 3; ++vt) {
        int id = vi[vt] + 1;
        const float* row = emb + (size_t)id * 128 + r * 8;  // lane r: 8 chans
        f4 e0 = *(const f4*)row;
        f4 e1 = *(const f4*)(row + 4);
        float ss = e0[0]*e0[0] + e0[1]*e0[1] + e0[2]*e0[2] + e0[3]*e0[3]
                 + e1[0]*e1[0] + e1[1]*e1[1] + e1[2]*e1[2] + e1[3]*e1[3];
        ss += __shfl_xor(ss, 1);             // reduce within the 16-lane group
        ss += __shfl_xor(ss, 2);
        ss += __shfl_xor(ss, 4);
        ss += __shfl_xor(ss, 8);
        float nrm = sqrtf(ss);
        float sc  = (nrm > 1.f) ? (1.f / (nrm + 1e-7f)) : 1.f;  // torch max_norm
        float wt  = by[vt] * sc;
#pragma unroll
        for (int j = 0; j < 4; ++j) { va[j] += wt * e0[j]; vb[j] += wt * e1[j]; }
      }
      h8 o;
#pragma unroll
      for (int j = 0; j < 4; ++j) { o[j] = (_Float16)va[j]; o[j+4] = (_Float16)vb[j]; }
      *(h8*)&X[p * RS + r * 8] = o;
    }
  };

  // ---- vde (K=18 padded to 32): in-place X update with race barrier
  {
    h8 Av[2];
#pragma unroll
    for (int ntl = 0; ntl < 2; ++ntl)
      Av[ntl] = *(const h8*)&ws[(nbase + ntl * 16 + r) * PRS + g * 8];
    h8 pe[4];
#pragma unroll
    for (int t = 0; t < 4; ++t) pe[t] = *(const h8*)&X[xr[t] + g * 8];
    __syncthreads();   // all PE reads in regs; X now writable
#pragma unroll
    for (int ntl = 0; ntl < 2; ++ntl) {
      f4 bini = *(const f4*)&BL[nbase + ntl * 16 + 4 * g];
      const int col = nbase + ntl * 16 + 4 * g;
#pragma unroll
      for (int t = 0; t < 4; ++t) {
        f4 acc = MFMA16(Av[ntl], pe[t], bini, 0, 0, 0);
        *(uint2*)&X[xr[t] + col] =          // no relu on vde output
          make_uint2(pkrtz(acc[0], acc[1]), pkrtz(acc[2], acc[3]));
      }
    }
  }
  __syncthreads();   // X (vde out) published

  // ---- 11 full 128x128 layers, in-place X, 2 barriers/layer
  u32 vhp[4][2][2];            // captured vh: set at li==2, used at li==5
  h8 Ar0[4], Ar1[4];           // 2-slot ring (32 VGPRs)
  LAYER(0);  LAYER(1);  LAYER(2);  LAYER(3);
  LAYER(4);  LAYER(5);  LAYER(6);  LAYER(7);
  LAYER(8);  LAYER(9);  LAYER(10);

  // ---- head_W2 (128 -> 4) + head_b2 from X; compiler-scheduled weights
  if (w == 0) {
    const u16* wa = ws + WOFF + 11 * FULLT;
    f4 b2 = *(const f4*)&BL[1536 + 4 * g];   // g==0 lanes: real head_b2
    f4 acc[4] = {b2, b2, b2, b2};
#pragma unroll
    for (int ks = 0; ks < 4; ++ks) {
      h8 A = *(const h8*)&wa[ks * 512 + lane * 8];
#pragma unroll
      for (int t = 0; t < 4; ++t) {
        h8 xt = *(const h8*)&X[xr[t] + ks * 32 + g * 8];
        acc[t] = MFMA16(A, xt, acc[t], 0, 0, 0);
      }
    }
    if (g == 0) {                      // lane r holds pixel r's rgba contiguously
#pragma unroll
      for (int t = 0; t < 4; ++t)
        *(f4*)&out[(bpix + t * 16 + r) * 4] = acc[t];
    }
  }
}

// ---------------------------------------------------------------------------
extern "C" void kernel_launch(void* const* d_in, const int* in_sizes, int n_in,
                              void* d_out, int out_size, void* d_ws, size_t ws_size,
                              hipStream_t stream) {
  const int*   vert    = (const int*)  d_in[0];
  const float* bary    = (const float*)d_in[1];
  const float* view    = (const float*)d_in[2];
  const float* emb     = (const float*)d_in[3];
  const float* vde_W   = (const float*)d_in[4];
  const float* vde_b   = (const float*)d_in[5];
  const float* vh_W    = (const float*)d_in[6];
  const float* vh_b    = (const float*)d_in[7];
  const float* hid_W   = (const float*)d_in[8];
  const float* hid_b   = (const float*)d_in[9];
  const float* head_W0 = (const float*)d_in[10];
  const float* head_b0 = (const float*)d_in[11];
  const float* head_W1 = (const float*)d_in[12];
  const float* head_b1 = (const float*)d_in[13];
  const float* head_W2 = (const float*)d_in[14];
  const float* head_b2 = (const float*)d_in[15];
  u16* wsp = (u16*)d_ws;   // needs 403456 B

  rc_prep<<<788, 256, 0, stream>>>(vde_W, vh_W, hid_W, head_W0, head_W1, head_W2, wsp);
  rc_main<<<8192, 256, 0, stream>>>(vert, bary, view, emb, vde_b, vh_b, hid_b,
                                    head_b0, head_b1, head_b2, wsp, (float*)d_out);
}